// Round 8
// baseline (196.340 us; speedup 1.0000x reference)
//
#include <hip/hip_runtime.h>
#include <math.h>

// Problem constants (fixed by reference)
#define BB 32     // batch
#define CC 512    // channels
#define CQ 64     // qk channels
#define NN 1024   // Nq = Nk = 32*32

typedef __attribute__((ext_vector_type(8))) short short8;   // 8 bf16 = 4 VGPR
typedef __attribute__((ext_vector_type(4))) float f32x4;    // MFMA C/D frag

#define MFMA16(a, b, c) __builtin_amdgcn_mfma_f32_16x16x32_bf16(a, b, c, 0, 0, 0)

// P strip LDS row stride (ushorts): 256 m + 8 pad = 264 (528 B)
#define PSTR 264
#define PBUF (64 * PSTR)   // one strip buffer, ushorts
// Znorm row stride (ushorts): 512 c + 8 pad
#define ZSTR 520
// audio_b row stride in elems: 1024 + 32 -> 2112 B, breaks 2KB L2 set aliasing
#define ASTR 1056

__device__ __forceinline__ ushort f2bf(float f) {
    uint u = __builtin_bit_cast(uint, f);
    return (ushort)((u + 0x7FFFu + ((u >> 16) & 1u)) >> 16);  // RNE
}
__device__ __forceinline__ short8 ld8(const ushort* p) {
    return *reinterpret_cast<const short8*>(p);
}

// ---------------------------------------------------------------------------
// All three weight tensors f32 -> bf16 in one launch. grid 320 x 256 exact.
// ---------------------------------------------------------------------------
__global__ __launch_bounds__(256) void k_cvt3(const float* __restrict__ Wq,
                                              const float* __restrict__ Wk,
                                              const float* __restrict__ Wv,
                                              ushort* __restrict__ Wqb,
                                              ushort* __restrict__ Wkb,
                                              ushort* __restrict__ Wvb) {
    int i = blockIdx.x * 256 + threadIdx.x;  // f4 index over 81920
    const float* src;
    ushort* dst;
    int off;
    if (i < 8192) { src = Wq; dst = Wqb; off = i; }
    else if (i < 16384) { src = Wk; dst = Wkb; off = i - 8192; }
    else { src = Wv; dst = Wvb; off = i - 16384; }
    float4 v = reinterpret_cast<const float4*>(src)[off];
    ushort4 o;
    o.x = f2bf(v.x); o.y = f2bf(v.y); o.z = f2bf(v.z); o.w = f2bf(v.w);
    reinterpret_cast<ushort4*>(dst)[off] = o;
}

// ---------------------------------------------------------------------------
// Qt[b][n][cq] = sum_c src[b][c][n]*W[cq][c] + bias[cq]   (bf16 out)
// sel=1 additionally emits audio_b (bf16 copy, ASTR-padded rows).
// grid (16 ntiles, 2 sel, B), block 256 (4 waves).
// ---------------------------------------------------------------------------
__global__ __launch_bounds__(256) void k_proj(const float* __restrict__ face,
                                              const float* __restrict__ audio,
                                              const ushort* __restrict__ Wqb,
                                              const float* __restrict__ bq,
                                              const ushort* __restrict__ Wkb,
                                              const float* __restrict__ bk,
                                              ushort* __restrict__ Qt,
                                              ushort* __restrict__ Kt,
                                              ushort* __restrict__ audio_b) {
    const int sel = blockIdx.y;
    const int b = blockIdx.z;
    const int n0 = blockIdx.x * 64;
    const float* src = sel ? audio : face;
    const ushort* Wb = sel ? Wkb : Wqb;
    const float* bias = sel ? bk : bq;
    ushort* dst = sel ? Kt : Qt;

    __shared__ float ldsT[64][65];  // [c][n], pad 1 -> 2-way max (free)
    const int t = threadIdx.x;
    const int w = __builtin_amdgcn_readfirstlane(t >> 6);  // wave 0..3
    const int l15 = t & 15;
    const int l4 = (t & 63) >> 4;

    f32x4 qacc[4];
#pragma unroll
    for (int j = 0; j < 4; ++j) qacc[j] = (f32x4){0.f, 0.f, 0.f, 0.f};

    for (int c0 = 0; c0 < CC; c0 += 64) {
        __syncthreads();
#pragma unroll
        for (int p = 0; p < 4; ++p) {
            int i = t + p * 256;          // 0..1023 float4s
            int c = i >> 4, n4 = (i & 15) * 4;
            float4 v = *reinterpret_cast<const float4*>(
                &src[((size_t)b * CC + c0 + c) * NN + n0 + n4]);
            ldsT[c][n4 + 0] = v.x;
            ldsT[c][n4 + 1] = v.y;
            ldsT[c][n4 + 2] = v.z;
            ldsT[c][n4 + 3] = v.w;
            if (sel) {
                ushort4 u;
                u.x = f2bf(v.x); u.y = f2bf(v.y); u.z = f2bf(v.z); u.w = f2bf(v.w);
                *reinterpret_cast<ushort4*>(
                    &audio_b[((size_t)b * CC + c0 + c) * ASTR + n0 + n4]) = u;
            }
        }
        __syncthreads();
#pragma unroll
        for (int ksub = 0; ksub < 2; ++ksub) {
            short8 af;
#pragma unroll
            for (int j = 0; j < 8; ++j)
                af[j] = (short)f2bf(ldsT[32 * ksub + 8 * l4 + j][16 * w + l15]);
#pragma unroll
            for (int cqj = 0; cqj < 4; ++cqj) {
                short8 wb = ld8(&Wb[(size_t)(16 * cqj + l15) * CC + c0 + 32 * ksub + 8 * l4]);
                qacc[cqj] = MFMA16(af, wb, qacc[cqj]);
            }
        }
    }
#pragma unroll
    for (int cqj = 0; cqj < 4; ++cqj) {
        float bs = bias[16 * cqj + l15];
#pragma unroll
        for (int reg = 0; reg < 4; ++reg) {
            int n = n0 + 16 * w + 4 * l4 + reg;
            dst[((size_t)b * NN + n) * CQ + 16 * cqj + l15] =
                f2bf(qacc[cqj][reg] + bs);
        }
    }
}

// ---------------------------------------------------------------------------
// Fused attention + output GEMM. One block per (b, 64-n-tile): grid 512,
// block 256 (4 waves), 2 blocks/CU, 2 waves/SIMD (256-reg budget).
// Per strip (256 m): S(t+1) detached (kb 1-chunk-ahead dbuf, qa resident),
// then Z(t) with af 1-deep cross-iteration prefetch (named-buffer dbuf so
// MFMA(ks) waits only on its own loads -- no full vmcnt drains). One barrier
// per strip. Softmax row-sums in registers. O = Wv.Znorm fused, wa dbuf.
// ---------------------------------------------------------------------------
__global__ __launch_bounds__(256, 2) void k_attn(
    const ushort* __restrict__ Qt, const ushort* __restrict__ Kt,
    const ushort* __restrict__ Ab_, const ushort* __restrict__ Wvb,
    const float* __restrict__ bv, const float* __restrict__ gamma,
    const float* __restrict__ face, float* __restrict__ out) {
    __shared__ ushort smem[2 * PBUF];  // P dbuf; aliased as Znorm [64][ZSTR]
    __shared__ float l_part[4][64];

    // bijective XCD-chunked swizzle: XCD x gets b in [4x, 4x+4)
    const int wg = blockIdx.x;
    const int swz = (wg & 7) * 64 + (wg >> 3);
    const int b = swz >> 4;
    const int n0 = (swz & 15) * 64;

    const int t = threadIdx.x;
    const int w = __builtin_amdgcn_readfirstlane(t >> 6);  // wave 0..3
    const int l15 = t & 15;
    const int l4 = (t & 63) >> 4;

    const ushort* Qb = Qt + ((size_t)b * NN + n0) * CQ;
    const ushort* Kb = Kt + (size_t)b * NN * CQ;
    const ushort* Ab = Ab_ + (size_t)b * CC * ASTR;

    f32x4 acc[8][4];   // Z: c = 128w+16ci+4l4+reg, n = 16nj+l15  (128 accum)
#pragma unroll
    for (int ci = 0; ci < 8; ++ci)
#pragma unroll
        for (int nj = 0; nj < 4; ++nj) acc[ci][nj] = (f32x4){0.f, 0.f, 0.f, 0.f};
    float lacc[4][4];  // P row-sums (rows 16ni+4l4+r, this wave's m-cols)
#pragma unroll
    for (int ni = 0; ni < 4; ++ni)
#pragma unroll
        for (int r = 0; r < 4; ++r) lacc[ni][r] = 0.f;

    // Q A-fragments resident for the whole kernel (32 VGPR)
    short8 qa[4][2];
#pragma unroll
    for (int ni = 0; ni < 4; ++ni)
#pragma unroll
        for (int kk = 0; kk < 2; ++kk)
            qa[ni][kk] = ld8(&Qb[(size_t)(16 * ni + l15) * CQ + 32 * kk + 8 * l4]);

    // One S chunk: 16 m-cols (16*mj of this wave's 64), kb passed in regs
#define S_ONE(wbuf, mj, KB0, KB1)                                              \
    _Pragma("unroll") for (int ni = 0; ni < 4; ++ni) {                         \
        f32x4 sacc = (f32x4){0.f, 0.f, 0.f, 0.f};                              \
        sacc = MFMA16(qa[ni][0], KB0, sacc);                                   \
        sacc = MFMA16(qa[ni][1], KB1, sacc);                                   \
        _Pragma("unroll") for (int r = 0; r < 4; ++r) {                        \
            float p = exp2f(sacc[r] * 0.18033688011112f);                      \
            lacc[ni][r] += p;                                                  \
            (wbuf)[(16 * ni + 4 * l4 + r) * PSTR + 64 * w + 16 * (mj) + l15] = \
                f2bf(p);                                                       \
        }                                                                      \
    }

    // Full S strip: 4 chunks, kb prefetched 1 chunk ahead (named dbuf)
#define S_STRIP(m0s, wbuf)                                                     \
    {                                                                          \
        const ushort* kbase = &Kb[(size_t)((m0s) + 64 * w + l15) * CQ + 8 * l4];\
        short8 kA0 = ld8(kbase), kA1 = ld8(kbase + 32);                        \
        short8 kB0 = ld8(kbase + 16 * CQ), kB1 = ld8(kbase + 16 * CQ + 32);    \
        S_ONE(wbuf, 0, kA0, kA1)                                               \
        kA0 = ld8(kbase + 32 * CQ); kA1 = ld8(kbase + 32 * CQ + 32);           \
        S_ONE(wbuf, 1, kB0, kB1)                                               \
        kB0 = ld8(kbase + 48 * CQ); kB1 = ld8(kbase + 48 * CQ + 32);           \
        S_ONE(wbuf, 2, kA0, kA1)                                               \
        S_ONE(wbuf, 3, kB0, kB1)                                               \
    }

    // Z helpers: af loads for one ks into a named buffer; MFMA consumes one
#define Z_LOAD(dst, kss)                                                       \
    _Pragma("unroll") for (int ci = 0; ci < 8; ++ci)                           \
        dst[ci] = ld8(&Ab[(size_t)(128 * w + 16 * ci + l15) * ASTR + m0r +     \
                          32 * (kss) + 8 * l4]);

#define Z_MFMA(src, kss)                                                       \
    {                                                                          \
        short8 pb[4];                                                          \
        _Pragma("unroll") for (int nj = 0; nj < 4; ++nj)                       \
            pb[nj] = ld8(&rbuf[(16 * nj + l15) * PSTR + 32 * (kss) + 8 * l4]); \
        __builtin_amdgcn_s_setprio(1);                                         \
        _Pragma("unroll") for (int ci = 0; ci < 8; ++ci)                       \
            _Pragma("unroll") for (int nj = 0; nj < 4; ++nj)                   \
                acc[ci][nj] = MFMA16(src[ci], pb[nj], acc[ci][nj]);            \
        __builtin_amdgcn_s_setprio(0);                                         \
    }

    // ---- prologue: S strip 0 into buf0
    S_STRIP(0, smem)
    __syncthreads();

    // ---- main loop over 4 strips
#pragma unroll 1
    for (int tt = 0; tt < 4; ++tt) {
        ushort* rbuf = smem + (tt & 1) * PBUF;
        ushort* wbuf = smem + ((tt + 1) & 1) * PBUF;
        const int m0r = tt * 256;
        if (tt < 3) S_STRIP(256 * (tt + 1), wbuf)
        {
            short8 afA[8], afB[8];
            Z_LOAD(afA, 0)
            Z_LOAD(afB, 1) Z_MFMA(afA, 0)
            Z_LOAD(afA, 2) Z_MFMA(afB, 1)
            Z_LOAD(afB, 3) Z_MFMA(afA, 2)
            Z_LOAD(afA, 4) Z_MFMA(afB, 3)
            Z_LOAD(afB, 5) Z_MFMA(afA, 4)
            Z_LOAD(afA, 6) Z_MFMA(afB, 5)
            Z_LOAD(afB, 7) Z_MFMA(afA, 6)
            Z_MFMA(afB, 7)
        }
        __syncthreads();
    }

    // ---- softmax denominators: reduce lacc over l15 (m within wave), share
#pragma unroll
    for (int ni = 0; ni < 4; ++ni)
#pragma unroll
        for (int r = 0; r < 4; ++r) {
            float v = lacc[ni][r];
            v += __shfl_xor(v, 1, 64);
            v += __shfl_xor(v, 2, 64);
            v += __shfl_xor(v, 4, 64);
            v += __shfl_xor(v, 8, 64);
            if (l15 == 0) l_part[w][16 * ni + 4 * l4 + r] = v;
        }
    __syncthreads();

    // ---- normalize + stage Znorm over the (now dead) P buffers as [n][c]
    float li[4];
#pragma unroll
    for (int nj = 0; nj < 4; ++nj) {
        int n = 16 * nj + l15;
        li[nj] = 1.f / (l_part[0][n] + l_part[1][n] + l_part[2][n] + l_part[3][n]);
    }
#pragma unroll
    for (int ci = 0; ci < 8; ++ci)
#pragma unroll
        for (int nj = 0; nj < 4; ++nj) {
            ushort4 o4;
            o4.x = f2bf(acc[ci][nj][0] * li[nj]);
            o4.y = f2bf(acc[ci][nj][1] * li[nj]);
            o4.z = f2bf(acc[ci][nj][2] * li[nj]);
            o4.w = f2bf(acc[ci][nj][3] * li[nj]);
            *reinterpret_cast<ushort4*>(
                &smem[(16 * nj + l15) * ZSTR + 128 * w + 16 * ci + 4 * l4]) = o4;
        }
    __syncthreads();

    // ---- O phase: wave w owns o-rows [128w,+128) x all 64 n; wa dbuf
#pragma unroll
    for (int oi = 0; oi < 8; ++oi)
#pragma unroll
        for (int nj = 0; nj < 4; ++nj) acc[oi][nj] = (f32x4){0.f, 0.f, 0.f, 0.f};
    short8 wap[2][8];
#pragma unroll
    for (int oi = 0; oi < 8; ++oi)
        wap[0][oi] = ld8(&Wvb[(size_t)(128 * w + 16 * oi + l15) * CC + 8 * l4]);
#pragma unroll 2
    for (int ks = 0; ks < 16; ++ks) {
        const int cur = ks & 1;
        if (ks < 15) {
#pragma unroll
            for (int oi = 0; oi < 8; ++oi)
                wap[cur ^ 1][oi] = ld8(&Wvb[(size_t)(128 * w + 16 * oi + l15) * CC +
                                            32 * (ks + 1) + 8 * l4]);
        }
        short8 zb[4];
#pragma unroll
        for (int nj = 0; nj < 4; ++nj)
            zb[nj] = ld8(&smem[(16 * nj + l15) * ZSTR + 32 * ks + 8 * l4]);
        __builtin_amdgcn_s_setprio(1);
#pragma unroll
        for (int oi = 0; oi < 8; ++oi)
#pragma unroll
            for (int nj = 0; nj < 4; ++nj)
                acc[oi][nj] = MFMA16(zb[nj], wap[cur][oi], acc[oi][nj]);
        __builtin_amdgcn_s_setprio(0);
    }

    // ---- epilogue: float4 along n
    const float g = gamma[0];
#pragma unroll
    for (int oi = 0; oi < 8; ++oi) {
        int o = 128 * w + 16 * oi + l15;
        float bvo = bv[o];
#pragma unroll
        for (int nj = 0; nj < 4; ++nj) {
            int n = n0 + 16 * nj + 4 * l4;
            size_t idx = ((size_t)b * CC + o) * NN + n;
            float4 fc = *reinterpret_cast<const float4*>(&face[idx]);
            float4 ov;
            ov.x = g * (acc[oi][nj][0] + bvo) + fc.x;
            ov.y = g * (acc[oi][nj][1] + bvo) + fc.y;
            ov.z = g * (acc[oi][nj][2] + bvo) + fc.z;
            ov.w = g * (acc[oi][nj][3] + bvo) + fc.w;
            *reinterpret_cast<float4*>(&out[idx]) = ov;
        }
    }
#undef S_ONE
#undef S_STRIP
#undef Z_LOAD
#undef Z_MFMA
}

// ---------------------------------------------------------------------------
extern "C" void kernel_launch(void* const* d_in, const int* in_sizes, int n_in,
                              void* d_out, int out_size, void* d_ws, size_t ws_size,
                              hipStream_t stream) {
    const float* face  = (const float*)d_in[0];
    const float* audio = (const float*)d_in[1];
    const float* Wq    = (const float*)d_in[2];
    const float* bq    = (const float*)d_in[3];
    const float* Wk    = (const float*)d_in[4];
    const float* bk    = (const float*)d_in[5];
    const float* Wv    = (const float*)d_in[6];
    const float* bv    = (const float*)d_in[7];
    const float* gamma = (const float*)d_in[8];
    float* out = (float*)d_out;
    char* ws = (char*)d_ws;

    // workspace layout (bytes)
    ushort* Qt      = (ushort*)(ws + 0);                       // 4 MB
    ushort* Kt      = (ushort*)(ws + (4u << 20));              // 4 MB
    ushort* audio_b = (ushort*)(ws + (8u << 20));              // ~33 MB (padded)
    ushort* Wqb     = (ushort*)(ws + (44u << 20));             // 64 KB
    ushort* Wkb     = (ushort*)(ws + (44u << 20) + (64u << 10));
    ushort* Wvb     = (ushort*)(ws + (44u << 20) + (128u << 10));  // 512 KB

    hipLaunchKernelGGL(k_cvt3, dim3(320), dim3(256), 0, stream,
                       Wq, Wk, Wv, Wqb, Wkb, Wvb);
    hipLaunchKernelGGL(k_proj, dim3(16, 2, BB), dim3(256), 0, stream,
                       face, audio, Wqb, bq, Wkb, bk, Qt, Kt, audio_b);
    hipLaunchKernelGGL(k_attn, dim3(512), dim3(256), 0, stream,
                       Qt, Kt, audio_b, Wvb, bv, gamma, face, out);
}

// Round 9
// 194.954 us; speedup vs baseline: 1.0071x; 1.0071x over previous
//
#include <hip/hip_runtime.h>
#include <math.h>

// Problem constants (fixed by reference)
#define BB 32     // batch
#define CC 512    // channels
#define CQ 64     // qk channels
#define NN 1024   // Nq = Nk = 32*32

typedef __attribute__((ext_vector_type(8))) short short8;   // 8 bf16 = 4 VGPR
typedef __attribute__((ext_vector_type(4))) float f32x4;    // MFMA C/D frag

#define MFMA16(a, b, c) __builtin_amdgcn_mfma_f32_16x16x32_bf16(a, b, c, 0, 0, 0)

// P strip LDS row stride (ushorts): 256 m + 8 pad = 264 (528 B)
#define PSTR 264
#define PBUF (64 * PSTR)   // one strip buffer, ushorts
// Znorm row stride (ushorts): 512 c + 8 pad
#define ZSTR 520
// audio_b row stride in elems: 1024 + 32 -> 2112 B, breaks 2KB L2 set aliasing
#define ASTR 1056

__device__ __forceinline__ ushort f2bf(float f) {
    uint u = __builtin_bit_cast(uint, f);
    return (ushort)((u + 0x7FFFu + ((u >> 16) & 1u)) >> 16);  // RNE
}
__device__ __forceinline__ short8 ld8(const ushort* p) {
    return *reinterpret_cast<const short8*>(p);
}

// ---------------------------------------------------------------------------
// All three weight tensors f32 -> bf16 in one launch. grid 320 x 256 exact.
// ---------------------------------------------------------------------------
__global__ __launch_bounds__(256) void k_cvt3(const float* __restrict__ Wq,
                                              const float* __restrict__ Wk,
                                              const float* __restrict__ Wv,
                                              ushort* __restrict__ Wqb,
                                              ushort* __restrict__ Wkb,
                                              ushort* __restrict__ Wvb) {
    int i = blockIdx.x * 256 + threadIdx.x;  // f4 index over 81920
    const float* src;
    ushort* dst;
    int off;
    if (i < 8192) { src = Wq; dst = Wqb; off = i; }
    else if (i < 16384) { src = Wk; dst = Wkb; off = i - 8192; }
    else { src = Wv; dst = Wvb; off = i - 16384; }
    float4 v = reinterpret_cast<const float4*>(src)[off];
    ushort4 o;
    o.x = f2bf(v.x); o.y = f2bf(v.y); o.z = f2bf(v.z); o.w = f2bf(v.w);
    reinterpret_cast<ushort4*>(dst)[off] = o;
}

// ---------------------------------------------------------------------------
// Qt[b][n][cq] = sum_c src[b][c][n]*W[cq][c] + bias[cq]   (bf16 out)
// sel=1 additionally emits audio_b (bf16 copy, ASTR-padded rows).
// grid (16 ntiles, 2 sel, B), block 256 (4 waves).
// ---------------------------------------------------------------------------
__global__ __launch_bounds__(256) void k_proj(const float* __restrict__ face,
                                              const float* __restrict__ audio,
                                              const ushort* __restrict__ Wqb,
                                              const float* __restrict__ bq,
                                              const ushort* __restrict__ Wkb,
                                              const float* __restrict__ bk,
                                              ushort* __restrict__ Qt,
                                              ushort* __restrict__ Kt,
                                              ushort* __restrict__ audio_b) {
    const int sel = blockIdx.y;
    const int b = blockIdx.z;
    const int n0 = blockIdx.x * 64;
    const float* src = sel ? audio : face;
    const ushort* Wb = sel ? Wkb : Wqb;
    const float* bias = sel ? bk : bq;
    ushort* dst = sel ? Kt : Qt;

    __shared__ float ldsT[64][65];  // [c][n], pad 1 -> 2-way max (free)
    const int t = threadIdx.x;
    const int w = __builtin_amdgcn_readfirstlane(t >> 6);  // wave 0..3
    const int l15 = t & 15;
    const int l4 = (t & 63) >> 4;

    f32x4 qacc[4];
#pragma unroll
    for (int j = 0; j < 4; ++j) qacc[j] = (f32x4){0.f, 0.f, 0.f, 0.f};

    for (int c0 = 0; c0 < CC; c0 += 64) {
        __syncthreads();
#pragma unroll
        for (int p = 0; p < 4; ++p) {
            int i = t + p * 256;          // 0..1023 float4s
            int c = i >> 4, n4 = (i & 15) * 4;
            float4 v = *reinterpret_cast<const float4*>(
                &src[((size_t)b * CC + c0 + c) * NN + n0 + n4]);
            ldsT[c][n4 + 0] = v.x;
            ldsT[c][n4 + 1] = v.y;
            ldsT[c][n4 + 2] = v.z;
            ldsT[c][n4 + 3] = v.w;
            if (sel) {
                ushort4 u;
                u.x = f2bf(v.x); u.y = f2bf(v.y); u.z = f2bf(v.z); u.w = f2bf(v.w);
                *reinterpret_cast<ushort4*>(
                    &audio_b[((size_t)b * CC + c0 + c) * ASTR + n0 + n4]) = u;
            }
        }
        __syncthreads();
#pragma unroll
        for (int ksub = 0; ksub < 2; ++ksub) {
            short8 af;
#pragma unroll
            for (int j = 0; j < 8; ++j)
                af[j] = (short)f2bf(ldsT[32 * ksub + 8 * l4 + j][16 * w + l15]);
#pragma unroll
            for (int cqj = 0; cqj < 4; ++cqj) {
                short8 wb = ld8(&Wb[(size_t)(16 * cqj + l15) * CC + c0 + 32 * ksub + 8 * l4]);
                qacc[cqj] = MFMA16(af, wb, qacc[cqj]);
            }
        }
    }
#pragma unroll
    for (int cqj = 0; cqj < 4; ++cqj) {
        float bs = bias[16 * cqj + l15];
#pragma unroll
        for (int reg = 0; reg < 4; ++reg) {
            int n = n0 + 16 * w + 4 * l4 + reg;
            dst[((size_t)b * NN + n) * CQ + 16 * cqj + l15] =
                f2bf(qacc[cqj][reg] + bs);
        }
    }
}

// ---------------------------------------------------------------------------
// Fused attention + output GEMM. One block per (b, 64-n-tile): grid 512,
// block 256 (4 waves), 2 blocks/CU. Arch-VGPR budget: acc -> 128 AGPR;
// arch live <= ~110 in every phase (qa NOT resident -- reloaded per S chunk;
// that residency caused R8's spill).
// Per strip (256 m): detached S (kb 1-chunk-ahead dbuf), then Z with af
// 1-deep named-buffer prefetch (counted waits, no FIFO drains). One barrier
// per strip. Softmax row-sums in registers. O = Wv.Znorm fused, wa dbuf.
// ---------------------------------------------------------------------------
__global__ __launch_bounds__(256, 2) void k_attn(
    const ushort* __restrict__ Qt, const ushort* __restrict__ Kt,
    const ushort* __restrict__ Ab_, const ushort* __restrict__ Wvb,
    const float* __restrict__ bv, const float* __restrict__ gamma,
    const float* __restrict__ face, float* __restrict__ out) {
    __shared__ ushort smem[2 * PBUF];  // P dbuf; aliased as Znorm [64][ZSTR]
    __shared__ float l_part[4][64];

    // bijective XCD-chunked swizzle: XCD x gets b in [4x, 4x+4)
    const int wg = blockIdx.x;
    const int swz = (wg & 7) * 64 + (wg >> 3);
    const int b = swz >> 4;
    const int n0 = (swz & 15) * 64;

    const int t = threadIdx.x;
    const int w = __builtin_amdgcn_readfirstlane(t >> 6);  // wave 0..3
    const int l15 = t & 15;
    const int l4 = (t & 63) >> 4;

    const ushort* Qb = Qt + ((size_t)b * NN + n0) * CQ;
    const ushort* Kb = Kt + (size_t)b * NN * CQ;
    const ushort* Ab = Ab_ + (size_t)b * CC * ASTR;

    f32x4 acc[8][4];   // Z: c = 128w+16ci+4l4+reg, n = 16nj+l15  (128 AGPR)
#pragma unroll
    for (int ci = 0; ci < 8; ++ci)
#pragma unroll
        for (int nj = 0; nj < 4; ++nj) acc[ci][nj] = (f32x4){0.f, 0.f, 0.f, 0.f};
    float lacc[4][4];  // P row-sums (rows 16ni+4l4+r, this wave's m-cols)
#pragma unroll
    for (int ni = 0; ni < 4; ++ni)
#pragma unroll
        for (int r = 0; r < 4; ++r) lacc[ni][r] = 0.f;

    // One S chunk: 16 m-cols (16*mj of this wave's 64). qa reloaded per
    // chunk from L1 (NOT resident -- arch-reg budget).
#define S_ONE(wbuf, mj, KB0, KB1)                                              \
    _Pragma("unroll") for (int ni = 0; ni < 4; ++ni) {                         \
        const ushort* qp = &Qb[(size_t)(16 * ni + l15) * CQ + 8 * l4];         \
        short8 qa0 = ld8(qp);                                                  \
        short8 qa1 = ld8(qp + 32);                                             \
        f32x4 sacc = (f32x4){0.f, 0.f, 0.f, 0.f};                              \
        sacc = MFMA16(qa0, KB0, sacc);                                         \
        sacc = MFMA16(qa1, KB1, sacc);                                         \
        _Pragma("unroll") for (int r = 0; r < 4; ++r) {                        \
            float p = exp2f(sacc[r] * 0.18033688011112f);                      \
            lacc[ni][r] += p;                                                  \
            (wbuf)[(16 * ni + 4 * l4 + r) * PSTR + 64 * w + 16 * (mj) + l15] = \
                f2bf(p);                                                       \
        }                                                                      \
    }

    // Full S strip: 4 chunks, kb prefetched 1 chunk ahead (named dbuf)
#define S_STRIP(m0s, wbuf)                                                     \
    {                                                                          \
        const ushort* kbase = &Kb[(size_t)((m0s) + 64 * w + l15) * CQ + 8 * l4];\
        short8 kA0 = ld8(kbase), kA1 = ld8(kbase + 32);                        \
        short8 kB0 = ld8(kbase + 16 * CQ), kB1 = ld8(kbase + 16 * CQ + 32);    \
        S_ONE(wbuf, 0, kA0, kA1)                                               \
        kA0 = ld8(kbase + 32 * CQ); kA1 = ld8(kbase + 32 * CQ + 32);           \
        S_ONE(wbuf, 1, kB0, kB1)                                               \
        kB0 = ld8(kbase + 48 * CQ); kB1 = ld8(kbase + 48 * CQ + 32);           \
        S_ONE(wbuf, 2, kA0, kA1)                                               \
        S_ONE(wbuf, 3, kB0, kB1)                                               \
    }

    // Z helpers: af loads for one ks into a named buffer; MFMA consumes one
#define Z_LOAD(dst, kss)                                                       \
    _Pragma("unroll") for (int ci = 0; ci < 8; ++ci)                           \
        dst[ci] = ld8(&Ab[(size_t)(128 * w + 16 * ci + l15) * ASTR + m0r +     \
                          32 * (kss) + 8 * l4]);

#define Z_MFMA(src, kss)                                                       \
    {                                                                          \
        short8 pb[4];                                                          \
        _Pragma("unroll") for (int nj = 0; nj < 4; ++nj)                       \
            pb[nj] = ld8(&rbuf[(16 * nj + l15) * PSTR + 32 * (kss) + 8 * l4]); \
        __builtin_amdgcn_s_setprio(1);                                         \
        _Pragma("unroll") for (int ci = 0; ci < 8; ++ci)                       \
            _Pragma("unroll") for (int nj = 0; nj < 4; ++nj)                   \
                acc[ci][nj] = MFMA16(src[ci], pb[nj], acc[ci][nj]);            \
        __builtin_amdgcn_s_setprio(0);                                         \
    }

    // ---- prologue: S strip 0 into buf0
    S_STRIP(0, smem)
    __syncthreads();

    // ---- main loop over 4 strips
#pragma unroll 1
    for (int tt = 0; tt < 4; ++tt) {
        ushort* rbuf = smem + (tt & 1) * PBUF;
        ushort* wbuf = smem + ((tt + 1) & 1) * PBUF;
        const int m0r = tt * 256;
        if (tt < 3) S_STRIP(256 * (tt + 1), wbuf)
        {
            short8 afA[8], afB[8];
            Z_LOAD(afA, 0)
            Z_LOAD(afB, 1) Z_MFMA(afA, 0)
            Z_LOAD(afA, 2) Z_MFMA(afB, 1)
            Z_LOAD(afB, 3) Z_MFMA(afA, 2)
            Z_LOAD(afA, 4) Z_MFMA(afB, 3)
            Z_LOAD(afB, 5) Z_MFMA(afA, 4)
            Z_LOAD(afA, 6) Z_MFMA(afB, 5)
            Z_LOAD(afB, 7) Z_MFMA(afA, 6)
            Z_MFMA(afB, 7)
        }
        __syncthreads();
    }

    // ---- softmax denominators: reduce lacc over l15 (m within wave), share
#pragma unroll
    for (int ni = 0; ni < 4; ++ni)
#pragma unroll
        for (int r = 0; r < 4; ++r) {
            float v = lacc[ni][r];
            v += __shfl_xor(v, 1, 64);
            v += __shfl_xor(v, 2, 64);
            v += __shfl_xor(v, 4, 64);
            v += __shfl_xor(v, 8, 64);
            if (l15 == 0) l_part[w][16 * ni + 4 * l4 + r] = v;
        }
    __syncthreads();

    // ---- normalize + stage Znorm over the (now dead) P buffers as [n][c]
    float li[4];
#pragma unroll
    for (int nj = 0; nj < 4; ++nj) {
        int n = 16 * nj + l15;
        li[nj] = 1.f / (l_part[0][n] + l_part[1][n] + l_part[2][n] + l_part[3][n]);
    }
#pragma unroll
    for (int ci = 0; ci < 8; ++ci)
#pragma unroll
        for (int nj = 0; nj < 4; ++nj) {
            ushort4 o4;
            o4.x = f2bf(acc[ci][nj][0] * li[nj]);
            o4.y = f2bf(acc[ci][nj][1] * li[nj]);
            o4.z = f2bf(acc[ci][nj][2] * li[nj]);
            o4.w = f2bf(acc[ci][nj][3] * li[nj]);
            *reinterpret_cast<ushort4*>(
                &smem[(16 * nj + l15) * ZSTR + 128 * w + 16 * ci + 4 * l4]) = o4;
        }
    __syncthreads();

    // ---- O phase: wave w owns o-rows [128w,+128) x all 64 n; wa dbuf
#pragma unroll
    for (int oi = 0; oi < 8; ++oi)
#pragma unroll
        for (int nj = 0; nj < 4; ++nj) acc[oi][nj] = (f32x4){0.f, 0.f, 0.f, 0.f};
    short8 wap[2][8];
#pragma unroll
    for (int oi = 0; oi < 8; ++oi)
        wap[0][oi] = ld8(&Wvb[(size_t)(128 * w + 16 * oi + l15) * CC + 8 * l4]);
#pragma unroll 2
    for (int ks = 0; ks < 16; ++ks) {
        const int cur = ks & 1;
        if (ks < 15) {
#pragma unroll
            for (int oi = 0; oi < 8; ++oi)
                wap[cur ^ 1][oi] = ld8(&Wvb[(size_t)(128 * w + 16 * oi + l15) * CC +
                                            32 * (ks + 1) + 8 * l4]);
        }
        short8 zb[4];
#pragma unroll
        for (int nj = 0; nj < 4; ++nj)
            zb[nj] = ld8(&smem[(16 * nj + l15) * ZSTR + 32 * ks + 8 * l4]);
        __builtin_amdgcn_s_setprio(1);
#pragma unroll
        for (int oi = 0; oi < 8; ++oi)
#pragma unroll
            for (int nj = 0; nj < 4; ++nj)
                acc[oi][nj] = MFMA16(zb[nj], wap[cur][oi], acc[oi][nj]);
        __builtin_amdgcn_s_setprio(0);
    }

    // ---- epilogue: float4 along n
    const float g = gamma[0];
#pragma unroll
    for (int oi = 0; oi < 8; ++oi) {
        int o = 128 * w + 16 * oi + l15;
        float bvo = bv[o];
#pragma unroll
        for (int nj = 0; nj < 4; ++nj) {
            int n = n0 + 16 * nj + 4 * l4;
            size_t idx = ((size_t)b * CC + o) * NN + n;
            float4 fc = *reinterpret_cast<const float4*>(&face[idx]);
            float4 ov;
            ov.x = g * (acc[oi][nj][0] + bvo) + fc.x;
            ov.y = g * (acc[oi][nj][1] + bvo) + fc.y;
            ov.z = g * (acc[oi][nj][2] + bvo) + fc.z;
            ov.w = g * (acc[oi][nj][3] + bvo) + fc.w;
            *reinterpret_cast<float4*>(&out[idx]) = ov;
        }
    }
#undef S_ONE
#undef S_STRIP
#undef Z_LOAD
#undef Z_MFMA
}

// ---------------------------------------------------------------------------
extern "C" void kernel_launch(void* const* d_in, const int* in_sizes, int n_in,
                              void* d_out, int out_size, void* d_ws, size_t ws_size,
                              hipStream_t stream) {
    const float* face  = (const float*)d_in[0];
    const float* audio = (const float*)d_in[1];
    const float* Wq    = (const float*)d_in[2];
    const float* bq    = (const float*)d_in[3];
    const float* Wk    = (const float*)d_in[4];
    const float* bk    = (const float*)d_in[5];
    const float* Wv    = (const float*)d_in[6];
    const float* bv    = (const float*)d_in[7];
    const float* gamma = (const float*)d_in[8];
    float* out = (float*)d_out;
    char* ws = (char*)d_ws;

    // workspace layout (bytes)
    ushort* Qt      = (ushort*)(ws + 0);                       // 4 MB
    ushort* Kt      = (ushort*)(ws + (4u << 20));              // 4 MB
    ushort* audio_b = (ushort*)(ws + (8u << 20));              // ~33 MB (padded)
    ushort* Wqb     = (ushort*)(ws + (44u << 20));             // 64 KB
    ushort* Wkb     = (ushort*)(ws + (44u << 20) + (64u << 10));
    ushort* Wvb     = (ushort*)(ws + (44u << 20) + (128u << 10));  // 512 KB

    hipLaunchKernelGGL(k_cvt3, dim3(320), dim3(256), 0, stream,
                       Wq, Wk, Wv, Wqb, Wkb, Wvb);
    hipLaunchKernelGGL(k_proj, dim3(16, 2, BB), dim3(256), 0, stream,
                       face, audio, Wqb, bq, Wkb, bk, Qt, Kt, audio_b);
    hipLaunchKernelGGL(k_attn, dim3(512), dim3(256), 0, stream,
                       Qt, Kt, audio_b, Wvb, bv, gamma, face, out);
}